// Round 8
// baseline (30.624 us; speedup 1.0000x reference)
//
#include <hip/hip_runtime.h>
#include <hip/hip_bf16.h>

#define BLK 256

// Quaternion (.x=w, .y=v1, .z=v2, .w=v3) representing SU(2) matrix w*I - i*(v.sigma)
// with sigma = (pauli0, pauli1, pauli2) = (sz, sx, sy) from the reference; the basis
// e_a = -i*sigma_a satisfies the quaternion algebra (e1e2=e3 cyclic, verified), so
// the Hamilton product == matrix product. qmul(A,B) == A@B (A is the LATER factor).
__device__ __forceinline__ float4 qmul(const float4 A, const float4 B) {
    return make_float4(
        A.x*B.x - A.y*B.y - A.z*B.z - A.w*B.w,
        A.x*B.y + B.x*A.y + A.z*B.w - A.w*B.z,
        A.x*B.z + B.x*A.z + A.w*B.y - A.y*B.w,
        A.x*B.w + B.x*A.w + A.y*B.z - A.z*B.y);
}

__device__ __forceinline__ float4 qid() { return make_float4(1.f, 0.f, 0.f, 0.f); }

__device__ __forceinline__ float4 qnorm(const float4 q) {
    float n = rsqrtf(q.x*q.x + q.y*q.y + q.z*q.z + q.w*q.w);
    return make_float4(q.x*n, q.y*n, q.z*n, q.w*n);
}

// Per-step rotation quat: al = 0.01*alpha, theta=|al|, quat=(cos th, sinc(th)*al).
// theta <= ~0.07 here, so 4th-order Taylor is exact to ~1e-10.
__device__ __forceinline__ float4 dquat(float a0, float a1, float a2) {
    float x = a0 * 0.01f, y = a1 * 0.01f, z = a2 * 0.01f;
    float t2 = x*x + y*y + z*z;
    float c = 1.f - t2 * (0.5f - t2 * (1.f / 24.f));
    float f = 1.f - t2 * ((1.f / 6.f) - t2 * (1.f / 120.f));
    return make_float4(c, f*x, f*y, f*z);
}

// Apply M (quat) to complex 2-vector; returns (re0, im0, re1, im1).
// M = [[w - i v1, -v3 - i v2],[v3 - i v2, w + i v1]]
__device__ __forceinline__ float4 qapply(const float4 m, float s0r, float s1r,
                                         float s0i, float s1i) {
    float w = m.x, v1 = m.y, v2 = m.z, v3 = m.w;
    return make_float4(
        w*s0r + v1*s0i - v3*s1r + v2*s1i,
        w*s0i - v1*s0r - v2*s1r - v3*s1i,
        v3*s0r + v2*s0i + w*s1r - v1*s1i,
        v3*s0i - v2*s0r + w*s1i + v1*s1r);
}

// In-order Hillis-Steele inclusive scan across the block (op: later@earlier).
__device__ __forceinline__ float4 block_scan_incl(float4 v, float4* sh) {
    const int tid = threadIdx.x;
    sh[tid] = v;
    __syncthreads();
    #pragma unroll
    for (int d = 1; d < BLK; d <<= 1) {
        float4 other;
        bool act = tid >= d;
        if (act) other = sh[tid - d];
        __syncthreads();
        if (act) { v = qmul(v, other); sh[tid] = v; }
        __syncthreads();
    }
    return v;
}

// Compute the CH per-step quats d[] and their chunk product (d[CH-1]@...@d[0]).
template<int CH>
__device__ __forceinline__ float4 chunk_quats(const float* __restrict__ al,
                                              long long t, long long T,
                                              long long nchunk, float4* d, bool& full) {
    float4 q = qid();
    full = false;
    if (t >= nchunk) {
        #pragma unroll
        for (int j = 0; j < CH; ++j) d[j] = qid();
        return q;
    }
    if ((t + 1) * CH <= T) {
        full = true;
        const float4* ap = reinterpret_cast<const float4*>(al) + (size_t)t * (CH * 3 / 4);
        #pragma unroll
        for (int g = 0; g < CH / 8; ++g) {
            float4 v0 = ap[g*6+0], v1 = ap[g*6+1], v2 = ap[g*6+2];
            float4 v3 = ap[g*6+3], v4 = ap[g*6+4], v5 = ap[g*6+5];
            d[g*8+0] = dquat(v0.x, v0.y, v0.z);
            d[g*8+1] = dquat(v0.w, v1.x, v1.y);
            d[g*8+2] = dquat(v1.z, v1.w, v2.x);
            d[g*8+3] = dquat(v2.y, v2.z, v2.w);
            d[g*8+4] = dquat(v3.x, v3.y, v3.z);
            d[g*8+5] = dquat(v3.w, v4.x, v4.y);
            d[g*8+6] = dquat(v4.z, v4.w, v5.x);
            d[g*8+7] = dquat(v5.y, v5.z, v5.w);
        }
    } else {
        #pragma unroll
        for (int j = 0; j < CH; ++j) {
            long long k = t * CH + j;
            d[j] = (k < T) ? dquat(al[k*3], al[k*3+1], al[k*3+2]) : qid();
        }
    }
    #pragma unroll
    for (int j = 0; j < CH; ++j) q = qmul(d[j], q);
    return qnorm(q);
}

// Epilogue. OUTPUT: float32, 4M elements = REAL PARTS only, [T,2] row-major:
// outf[2k] = Re(out0(k)), outf[2k+1] = Re(out1(k)).
// (complex64 reference cast to float32 by the harness drops the imaginary part.)
// Chunk t = CH steps = 2*CH floats = CH/2 float4s; group g (8 steps) = 4 float4s.
template<int CH>
__device__ __forceinline__ void apply_and_store(
    const float4* d, float4 run, bool full, long long t, long long T,
    const float* __restrict__ sre, const float* __restrict__ sim,
    float* __restrict__ outf) {
    if (full) {
        const float4* rp = reinterpret_cast<const float4*>(sre) + (size_t)t * (CH / 2);
        const float4* ip = reinterpret_cast<const float4*>(sim) + (size_t)t * (CH / 2);
        float4* op = reinterpret_cast<float4*>(outf) + (size_t)t * (CH / 2);
        #pragma unroll
        for (int g = 0; g < CH / 8; ++g) {
            float4 r0 = rp[g*4+0], r1 = rp[g*4+1], r2 = rp[g*4+2], r3 = rp[g*4+3];
            float4 i0 = ip[g*4+0], i1 = ip[g*4+1], i2 = ip[g*4+2], i3 = ip[g*4+3];
            float4 p0, p1;
            run = qmul(d[g*8+0], run); p0 = qapply(run, r0.x, r0.y, i0.x, i0.y);
            run = qmul(d[g*8+1], run); p1 = qapply(run, r0.z, r0.w, i0.z, i0.w);
            op[g*4+0] = make_float4(p0.x, p0.z, p1.x, p1.z);
            run = qmul(d[g*8+2], run); p0 = qapply(run, r1.x, r1.y, i1.x, i1.y);
            run = qmul(d[g*8+3], run); p1 = qapply(run, r1.z, r1.w, i1.z, i1.w);
            op[g*4+1] = make_float4(p0.x, p0.z, p1.x, p1.z);
            run = qmul(d[g*8+4], run); p0 = qapply(run, r2.x, r2.y, i2.x, i2.y);
            run = qmul(d[g*8+5], run); p1 = qapply(run, r2.z, r2.w, i2.z, i2.w);
            op[g*4+2] = make_float4(p0.x, p0.z, p1.x, p1.z);
            run = qmul(d[g*8+6], run); p0 = qapply(run, r3.x, r3.y, i3.x, i3.y);
            run = qmul(d[g*8+7], run); p1 = qapply(run, r3.z, r3.w, i3.z, i3.w);
            op[g*4+3] = make_float4(p0.x, p0.z, p1.x, p1.z);
        }
    } else {
        float2* op2 = reinterpret_cast<float2*>(outf);
        #pragma unroll
        for (int j = 0; j < CH; ++j) {
            long long k = t * CH + j;
            if (k < T) {
                run = qmul(d[j], run);
                float4 p = qapply(run, sre[k*2], sre[k*2+1], sim[k*2], sim[k*2+1]);
                op2[k] = make_float2(p.x, p.z);   // (Re out0, Re out1)
            }
        }
    }
}

// K1: per-block aggregate A[b] only (workspace: nblk float4).
template<int CH>
__global__ void __launch_bounds__(BLK) pmd_k1(
    const float* __restrict__ al, float4* __restrict__ A,
    long long T, long long nchunk) {
    __shared__ float4 sh[BLK];
    const long long t = (long long)blockIdx.x * BLK + threadIdx.x;
    float4 d[CH];
    bool full;
    float4 q = chunk_quats<CH>(al, t, T, nchunk, d, full);
    float4 incl = block_scan_incl(q, sh);
    if (threadIdx.x == BLK - 1) A[blockIdx.x] = qnorm(incl);
}

// K2: one block. EB[b] = qnorm(A[b-1]@...@A[0]@q0), EB[0]=q0.
template<int EPT>
__global__ void __launch_bounds__(BLK) pmd_k2(
    const float4* __restrict__ A, float4* __restrict__ EB,
    const float* __restrict__ j0re, const float* __restrict__ j0im, int nblk) {
    __shared__ float4 sh[BLK];
    const int tid = threadIdx.x;
    float4 excl[EPT];
    float4 run = qid();
    #pragma unroll
    for (int e = 0; e < EPT; ++e) {
        int idx = tid * EPT + e;
        excl[e] = run;
        if (idx < nblk) run = qmul(A[idx], run);
    }
    block_scan_incl(run, sh);
    float4 X = (tid == 0) ? qid() : sh[tid - 1];
    // q0 from J0 = [[w - i v1, -v3 - i v2],[v3 - i v2, w + i v1]]
    float4 q0 = make_float4(j0re[0], -j0im[0], -j0im[1], -j0re[1]);
    float4 base = qmul(X, q0);
    #pragma unroll
    for (int e = 0; e < EPT; ++e) {
        int idx = tid * EPT + e;
        if (idx < nblk) EB[idx] = qnorm(qmul(excl[e], base));
    }
}

// K3: recompute chunk quats, block scan -> in-block exclusive prefix, compose
// with EB[b], walk chunk and emit float32 real-part output.
template<int CH>
__global__ void __launch_bounds__(BLK) pmd_k3(
    const float* __restrict__ al, const float* __restrict__ sre,
    const float* __restrict__ sim, const float4* __restrict__ EB,
    float* __restrict__ outf, long long T, long long nchunk) {
    __shared__ float4 sh[BLK];
    const long long t = (long long)blockIdx.x * BLK + threadIdx.x;
    float4 d[CH];
    bool full;
    float4 q = chunk_quats<CH>(al, t, T, nchunk, d, full);
    block_scan_incl(q, sh);
    float4 Xv = (threadIdx.x == 0) ? qid() : sh[threadIdx.x - 1];
    if (t >= nchunk) return;  // after all barriers
    float4 run = qmul(Xv, EB[blockIdx.x]);
    apply_and_store<CH>(d, run, full, t, T, sre, sim, outf);
}

// Zero-workspace fallback: one block walks the whole sequence in segments.
template<int CH>
__global__ void __launch_bounds__(BLK) pmd_mono(
    const float* __restrict__ al, const float* __restrict__ sre,
    const float* __restrict__ sim, const float* __restrict__ j0re,
    const float* __restrict__ j0im, float* __restrict__ outf, long long T) {
    __shared__ float4 sh[BLK];
    __shared__ float4 sbase;
    if (threadIdx.x == 0)
        sbase = make_float4(j0re[0], -j0im[0], -j0im[1], -j0re[1]);
    __syncthreads();
    const long long nchunk = (T + CH - 1) / CH;
    for (long long c0 = 0; c0 < nchunk; c0 += BLK) {
        const long long t = c0 + threadIdx.x;
        float4 d[CH];
        bool full;
        float4 q = chunk_quats<CH>(al, t, T, nchunk, d, full);
        float4 incl = block_scan_incl(q, sh);
        float4 Xv = (threadIdx.x == 0) ? qid() : sh[threadIdx.x - 1];
        float4 base = sbase;
        __syncthreads();
        if (threadIdx.x == BLK - 1) sbase = qnorm(qmul(incl, base));
        if (t < nchunk) {
            float4 run = qmul(Xv, base);
            apply_and_store<CH>(d, run, full, t, T, sre, sim, outf);
        }
        __syncthreads();
    }
}

extern "C" void kernel_launch(void* const* d_in, const int* in_sizes, int n_in,
                              void* d_out, int out_size, void* d_ws, size_t ws_size,
                              hipStream_t stream) {
    const float* sre  = (const float*)d_in[0];
    const float* sim  = (const float*)d_in[1];
    const float* al   = (const float*)d_in[2];
    const float* j0re = (const float*)d_in[3];
    const float* j0im = (const float*)d_in[4];
    float* outf = (float*)d_out;   // f32 out, 4M elems: real parts [T,2]
    long long T = (long long)in_sizes[2] / 3;
    if (T <= 0) return;

    constexpr int CH = 8;
    long long nchunk = (T + CH - 1) / CH;
    long long nblkLL = (nchunk + BLK - 1) / BLK;
    size_t need = (size_t)(2 * nblkLL) * sizeof(float4);

    if (ws_size >= need && nblkLL <= (long long)BLK * 16) {
        int nblk = (int)nblkLL;
        float4* A  = (float4*)d_ws;
        float4* EB = A + nblk;
        pmd_k1<CH><<<nblk, BLK, 0, stream>>>(al, A, T, nchunk);
        if      (nblk <= BLK)      pmd_k2<1> <<<1, BLK, 0, stream>>>(A, EB, j0re, j0im, nblk);
        else if (nblk <= 2 * BLK)  pmd_k2<2> <<<1, BLK, 0, stream>>>(A, EB, j0re, j0im, nblk);
        else if (nblk <= 4 * BLK)  pmd_k2<4> <<<1, BLK, 0, stream>>>(A, EB, j0re, j0im, nblk);
        else if (nblk <= 8 * BLK)  pmd_k2<8> <<<1, BLK, 0, stream>>>(A, EB, j0re, j0im, nblk);
        else                       pmd_k2<16><<<1, BLK, 0, stream>>>(A, EB, j0re, j0im, nblk);
        pmd_k3<CH><<<nblk, BLK, 0, stream>>>(al, sre, sim, EB, outf, T, nchunk);
    } else {
        pmd_mono<CH><<<1, BLK, 0, stream>>>(al, sre, sim, j0re, j0im, outf, T);
    }
}